// Round 4
// baseline (327.342 us; speedup 1.0000x reference)
//
#include <hip/hip_runtime.h>
#include <hip/hip_bf16.h>
#include <cstdint>
#include <cstddef>

typedef float  f32x4 __attribute__((ext_vector_type(4)));
typedef _Float16 f16x8 __attribute__((ext_vector_type(8)));

#define DEVFN __device__ __forceinline__

// ---------------------------------------------------------------------------
// Cubic B-spline basis on the UNIFORM grid: all knot gaps are p*h (constants),
// so the reference's divisions become multiplies by 1/(p*h).
// ---------------------------------------------------------------------------
DEVFN void bspline8(float x, float bv[8]) {
    float t[12];
#pragma unroll
    for (int j = 0; j < 12; ++j) t[j] = (float)(j - 3) * 0.4f - 1.0f;
    float B[11];
#pragma unroll
    for (int j = 0; j < 11; ++j) B[j] = (x >= t[j] && x < t[j + 1]) ? 1.0f : 0.0f;
    const float rp[3] = {2.5f, 1.25f, 0.8333333333f};  // 1/(p*0.4)
#pragma unroll
    for (int p = 1; p <= 3; ++p) {
#pragma unroll
        for (int j = 0; j + p < 11; ++j) {
            float left  = (x - t[j]) * rp[p - 1];
            float right = (t[j + p + 1] - x) * rp[p - 1];
            B[j] = left * B[j] + right * B[j + 1];
        }
    }
#pragma unroll
    for (int g = 0; g < 8; ++g) bv[g] = B[g];
}

// ---------------------------------------------------------------------------
// prep_a: X (Nrows x D, f32) -> Aaug (Nrows x 9*D, fp16), k = c*D + i
// ---------------------------------------------------------------------------
__global__ void prep_a_kernel(const float* __restrict__ X,
                              _Float16* __restrict__ Aaug,
                              int total, int dshift) {
    int idx = blockIdx.x * 256 + threadIdx.x;
    if (idx >= total) return;
    const int D = 1 << dshift;
    const int K = 9 << dshift;
    const int n = idx >> dshift;
    const int i = idx & (D - 1);
    float x = X[idx];
    float s = x * __builtin_amdgcn_rcpf(1.0f + __expf(-x));   // silu (fast)
    float bv[8];
    bspline8(x, bv);
    _Float16* dst = Aaug + (size_t)n * K + i;
    dst[0] = (_Float16)s;
#pragma unroll
    for (int g = 0; g < 8; ++g) dst[(size_t)(g + 1) * D] = (_Float16)bv[g];
}

// ---------------------------------------------------------------------------
// prep_w: coef (Din x Dout x 8), scale_base/scale_sp (Din x Dout)
//   -> WT (Dout x 9*Din, fp16)
// ---------------------------------------------------------------------------
__global__ void prep_w_kernel(const float* __restrict__ coef,
                              const float* __restrict__ sb,
                              const float* __restrict__ sp,
                              _Float16* __restrict__ WT,
                              int total, int din_shift, int dout) {
    int idx = blockIdx.x * 256 + threadIdx.x;
    if (idx >= total) return;
    const int Din = 1 << din_shift;
    const int i = idx & (Din - 1);
    const int o = idx >> din_shift;
    const size_t K = (size_t)9 << din_shift;
    const size_t cidx = (size_t)i * dout + o;
    float base  = sb[cidx];
    float scale = sp[cidx];
    const float* cp = coef + cidx * 8;
    _Float16* dst = WT + (size_t)o * K + i;
    dst[0] = (_Float16)base;
#pragma unroll
    for (int g = 0; g < 8; ++g) dst[(size_t)(g + 1) * Din] = (_Float16)(cp[g] * scale);
}

// ---------------------------------------------------------------------------
// GEMM 128x128 tile, BK=64, 4 waves (2x2), 4x4 16x16x32 f16 MFMA frags/wave.
// T2 XOR swizzle (linear LDS dest + pre-swizzled global source + swizzled
// ds_read). Split-K over decoded z, f32 atomic-add epilogue (C pre-zeroed).
// T1 XCD-aware block swizzle: nwg % 8 == 0 (bijective); gridDim.y must be 32.
// ---------------------------------------------------------------------------
DEVFN void gload16(const void* g, void* l) {
    __builtin_amdgcn_global_load_lds(
        (const __attribute__((address_space(1))) void*)g,
        (__attribute__((address_space(3))) void*)l, 16, 0, 0);
}

__global__ __launch_bounds__(256) void gemm128_f16_bt(
    const _Float16* __restrict__ A,
    const _Float16* __restrict__ WT,
    float* __restrict__ C,
    int K, int N, int klen, int gxshift) {
    constexpr int BK = 64;
    __shared__ _Float16 Alds[128 * BK];
    __shared__ _Float16 Blds[128 * BK];

    const int tid  = threadIdx.x;
    const int lane = tid & 63;
    const int w    = tid >> 6;
    const int wm   = w >> 1;
    const int wn   = w & 1;

    // ---- T1 XCD swizzle: orig dispatch id -> contiguous chunk per XCD ----
    const int gx   = 1 << gxshift;
    const int nwg  = gx * 32 * gridDim.z;
    const int orig = blockIdx.x + (blockIdx.y << gxshift) + blockIdx.z * (gx * 32);
    const int tile = (orig & 7) * (nwg >> 3) + (orig >> 3);
    const int col  = tile & (gx - 1);
    const int rs   = tile >> gxshift;
    const int row  = rs & 31;          // gridDim.y == 32
    const int spl  = rs >> 5;

    const size_t bm = (size_t)row * 128;
    const size_t bn = (size_t)col * 128;
    const int kbase = spl * klen;

    const f32x4 vzero = {0.0f, 0.0f, 0.0f, 0.0f};
    f32x4 acc[4][4];
#pragma unroll
    for (int m = 0; m < 4; ++m)
#pragma unroll
        for (int n = 0; n < 4; ++n) acc[m][n] = vzero;

    const int srow = tid >> 3;
    const int c8   = tid & 7;

    for (int k0 = kbase; k0 < kbase + klen; k0 += BK) {
#pragma unroll
        for (int is = 0; is < 4; ++is) {
            const int r  = is * 32 + srow;
            const int sg = (c8 ^ (r & 7)) << 3;  // swizzled source col (elems)
            gload16(A + (bm + r) * (size_t)K + k0 + sg,
                    Alds + is * 2048 + w * 512);
            gload16(WT + (bn + r) * (size_t)K + k0 + sg,
                    Blds + is * 2048 + w * 512);
        }
        __syncthreads();

#pragma unroll
        for (int ks = 0; ks < BK; ks += 32) {
            f16x8 af[4], bf[4];
            const int g = (ks >> 3) + (lane >> 4);      // k col-group 0..7
#pragma unroll
            for (int m = 0; m < 4; ++m) {
                const int r2 = wm * 64 + m * 16 + (lane & 15);
                af[m] = *(const f16x8*)(Alds + r2 * BK + ((g ^ (r2 & 7)) << 3));
            }
#pragma unroll
            for (int n = 0; n < 4; ++n) {
                const int r2 = wn * 64 + n * 16 + (lane & 15);
                bf[n] = *(const f16x8*)(Blds + r2 * BK + ((g ^ (r2 & 7)) << 3));
            }
#pragma unroll
            for (int m = 0; m < 4; ++m)
#pragma unroll
                for (int n = 0; n < 4; ++n)
                    acc[m][n] = __builtin_amdgcn_mfma_f32_16x16x32_f16(
                        af[m], bf[n], acc[m][n], 0, 0, 0);
        }
        __syncthreads();
    }

    // epilogue: C/D layout col = lane&15, row = (lane>>4)*4 + reg  [m89]
    const int r0 = wm * 64 + (lane >> 4) * 4;
    const int c0 = wn * 64 + (lane & 15);
#pragma unroll
    for (int m = 0; m < 4; ++m)
#pragma unroll
        for (int n = 0; n < 4; ++n)
#pragma unroll
            for (int r = 0; r < 4; ++r)
                unsafeAtomicAdd(&C[(bm + r0 + m * 16 + r) * (size_t)N + bn + c0 + n * 16],
                                acc[m][n][r]);
}

// ---------------------------------------------------------------------------
// launch
// ---------------------------------------------------------------------------
extern "C" void kernel_launch(void* const* d_in, const int* in_sizes, int n_in,
                              void* d_out, int out_size, void* d_ws, size_t ws_size,
                              hipStream_t stream) {
    const float* x     = (const float*)d_in[0];
    const float* coef1 = (const float*)d_in[1];
    const float* sb1   = (const float*)d_in[2];
    const float* sp1   = (const float*)d_in[3];
    const float* coef2 = (const float*)d_in[4];
    const float* sb2   = (const float*)d_in[5];
    const float* sp2   = (const float*)d_in[6];
    float* out = (float*)d_out;

    const int M  = 4096;           // bsz*seq
    const int D1 = 512;            // d_model
    const int D2 = 1024;           // hidden
    const int K1 = 9 * D1;         // 4608
    const int K2 = 9 * D2;         // 9216

    char* ws = (char*)d_ws;
    float*    h    = (float*)ws;                                     // 16.78 MB
    _Float16* Aaug = (_Float16*)(ws + (size_t)M * D2 * 4);           // up to 75.5 MB
    _Float16* WT   = (_Float16*)(ws + (size_t)M * D2 * 4 + (size_t)M * K2 * 2); // 9.44 MB

    hipMemsetAsync(h, 0, (size_t)M * D2 * 4, stream);
    hipMemsetAsync(out, 0, (size_t)M * D1 * 4, stream);

    // ---- layer 1 ----
    prep_w_kernel<<<(D1 * D2) / 256, 256, 0, stream>>>(coef1, sb1, sp1, WT,
                                                       D1 * D2, 9, D2);
    prep_a_kernel<<<(M * D1) / 256, 256, 0, stream>>>(x, Aaug, M * D1, 9);
    {
        dim3 grid(D2 / 128, M / 128, 4);   // split-K x4 -> 1024 blocks (4/CU)
        gemm128_f16_bt<<<grid, 256, 0, stream>>>(Aaug, WT, h, K1, D2, K1 / 4, 3);
    }
    // ---- layer 2 ----
    prep_w_kernel<<<(D2 * D1) / 256, 256, 0, stream>>>(coef2, sb2, sp2, WT,
                                                       D1 * D2, 10, D1);
    prep_a_kernel<<<(M * D2) / 256, 256, 0, stream>>>(h, Aaug, M * D2, 10);
    {
        dim3 grid(D1 / 128, M / 128, 8);   // split-K x8 -> 1024 blocks (4/CU)
        gemm128_f16_bt<<<grid, 256, 0, stream>>>(Aaug, WT, out, K2, D1, K2 / 8, 2);
    }
}

// Round 5
// 279.053 us; speedup vs baseline: 1.1730x; 1.1730x over previous
//
#include <hip/hip_runtime.h>
#include <hip/hip_bf16.h>
#include <cstdint>
#include <cstddef>

typedef float  f32x4 __attribute__((ext_vector_type(4)));
typedef _Float16 f16x8 __attribute__((ext_vector_type(8)));

#define DEVFN __device__ __forceinline__

// ---------------------------------------------------------------------------
// Cubic B-spline basis on the UNIFORM grid (divisions -> constant multiplies).
// ---------------------------------------------------------------------------
DEVFN void bspline8(float x, float bv[8]) {
    float t[12];
#pragma unroll
    for (int j = 0; j < 12; ++j) t[j] = (float)(j - 3) * 0.4f - 1.0f;
    float B[11];
#pragma unroll
    for (int j = 0; j < 11; ++j) B[j] = (x >= t[j] && x < t[j + 1]) ? 1.0f : 0.0f;
    const float rp[3] = {2.5f, 1.25f, 0.8333333333f};  // 1/(p*0.4)
#pragma unroll
    for (int p = 1; p <= 3; ++p) {
#pragma unroll
        for (int j = 0; j + p < 11; ++j) {
            float left  = (x - t[j]) * rp[p - 1];
            float right = (t[j + p + 1] - x) * rp[p - 1];
            B[j] = left * B[j] + right * B[j + 1];
        }
    }
#pragma unroll
    for (int g = 0; g < 8; ++g) bv[g] = B[g];
}

// ---------------------------------------------------------------------------
// prep_a: X (Nrows x D, f32) -> Aaug (Nrows x 9*D, fp16), k = c*D + i
// ---------------------------------------------------------------------------
__global__ void prep_a_kernel(const float* __restrict__ X,
                              _Float16* __restrict__ Aaug,
                              int total, int dshift) {
    int idx = blockIdx.x * 256 + threadIdx.x;
    if (idx >= total) return;
    const int D = 1 << dshift;
    const int K = 9 << dshift;
    const int n = idx >> dshift;
    const int i = idx & (D - 1);
    float x = X[idx];
    float s = x * __builtin_amdgcn_rcpf(1.0f + __expf(-x));   // silu (fast)
    float bv[8];
    bspline8(x, bv);
    _Float16* dst = Aaug + (size_t)n * K + i;
    dst[0] = (_Float16)s;
#pragma unroll
    for (int g = 0; g < 8; ++g) dst[(size_t)(g + 1) * D] = (_Float16)bv[g];
}

// ---------------------------------------------------------------------------
// prep_w: coef (Din x Dout x 8), scale_base/scale_sp (Din x Dout)
//   -> WT (Dout x 9*Din, fp16)
// ---------------------------------------------------------------------------
__global__ void prep_w_kernel(const float* __restrict__ coef,
                              const float* __restrict__ sb,
                              const float* __restrict__ sp,
                              _Float16* __restrict__ WT,
                              int total, int din_shift, int dout) {
    int idx = blockIdx.x * 256 + threadIdx.x;
    if (idx >= total) return;
    const int Din = 1 << din_shift;
    const int i = idx & (Din - 1);
    const int o = idx >> din_shift;
    const size_t K = (size_t)9 << din_shift;
    const size_t cidx = (size_t)i * dout + o;
    float base  = sb[cidx];
    float scale = sp[cidx];
    const float* cp = coef + cidx * 8;
    _Float16* dst = WT + (size_t)o * K + i;
    dst[0] = (_Float16)base;
#pragma unroll
    for (int g = 0; g < 8; ++g) dst[(size_t)(g + 1) * Din] = (_Float16)(cp[g] * scale);
}

// ---------------------------------------------------------------------------
// GEMM 128x128, BK=64, 4 waves (2x2), 4x4 16x16x32 f16 MFMA frags/wave.
// T2 XOR swizzle (linear LDS dest via global_load_lds + pre-swizzled global
// source + swizzled ds_read). T3 minimum 2-phase pipeline: double-buffered
// LDS, next tile's loads issued BEFORE computing current tile, raw s_barrier
// + counted s_waitcnt vmcnt(8) so prefetch stays in flight across barriers.
// Split-K via decoded z, f32 atomic-add epilogue (C pre-zeroed).
// T1 XCD-aware block swizzle (bijective; nwg % 8 == 0, gridDim.y == 32).
// ---------------------------------------------------------------------------
DEVFN void gload16(const void* g, void* l) {
    __builtin_amdgcn_global_load_lds(
        (const __attribute__((address_space(1))) void*)g,
        (__attribute__((address_space(3))) void*)l, 16, 0, 0);
}

__global__ __launch_bounds__(256) void gemm128_f16_bt(
    const _Float16* __restrict__ A,
    const _Float16* __restrict__ WT,
    float* __restrict__ C,
    int K, int N, int klen, int gxshift) {
    constexpr int BK = 64;
    __shared__ _Float16 Alds[2][128 * BK];
    __shared__ _Float16 Blds[2][128 * BK];

    const int tid  = threadIdx.x;
    const int lane = tid & 63;
    const int w    = tid >> 6;
    const int wm   = w >> 1;
    const int wn   = w & 1;

    // ---- T1 XCD swizzle: orig dispatch id -> contiguous chunk per XCD ----
    const int gx   = 1 << gxshift;
    const int nwg  = gx * 32 * gridDim.z;
    const int orig = blockIdx.x + (blockIdx.y << gxshift) + blockIdx.z * (gx * 32);
    const int tile = (orig & 7) * (nwg >> 3) + (orig >> 3);
    const int col  = tile & (gx - 1);
    const int rs   = tile >> gxshift;
    const int row  = rs & 31;          // gridDim.y == 32
    const int spl  = rs >> 5;

    const size_t bm = (size_t)row * 128;
    const size_t bn = (size_t)col * 128;
    const int kbase = spl * klen;
    const int nt    = klen / BK;

    const f32x4 vzero = {0.0f, 0.0f, 0.0f, 0.0f};
    f32x4 acc[4][4];
#pragma unroll
    for (int m = 0; m < 4; ++m)
#pragma unroll
        for (int n = 0; n < 4; ++n) acc[m][n] = vzero;

    const int srow = tid >> 3;
    const int c8   = tid & 7;
    const int ldst = w * 512;           // wave-uniform LDS base (halfs)

    // issue the 8 async loads (4 A + 4 B) of K-tile kk into buffer b
#define STAGE(b, kk)                                                         \
    {                                                                        \
        _Pragma("unroll")                                                    \
        for (int is = 0; is < 4; ++is) {                                     \
            const int r  = is * 32 + srow;                                   \
            const int sg = (c8 ^ (r & 7)) << 3;                              \
            gload16(A + (bm + r) * (size_t)K + (kk) + sg,                    \
                    &Alds[b][is * 2048 + ldst]);                             \
            gload16(WT + (bn + r) * (size_t)K + (kk) + sg,                   \
                    &Blds[b][is * 2048 + ldst]);                             \
        }                                                                    \
    }

    STAGE(0, kbase);                     // prologue: buf0 in flight (8)

    for (int t = 0; t < nt; ++t) {
        const int cur = t & 1;
        if (t + 1 < nt) {
            STAGE(cur ^ 1, kbase + (t + 1) * BK);            // 16 in flight
            asm volatile("s_waitcnt vmcnt(8)" ::: "memory"); // cur's 8 done
        } else {
            asm volatile("s_waitcnt vmcnt(0)" ::: "memory");
        }
        __builtin_amdgcn_s_barrier();          // all waves: cur buffer ready
        __builtin_amdgcn_sched_barrier(0);

#pragma unroll
        for (int ks = 0; ks < BK; ks += 32) {
            f16x8 af[4], bf[4];
            const int g = (ks >> 3) + (lane >> 4);      // k col-group 0..7
#pragma unroll
            for (int m = 0; m < 4; ++m) {
                const int r2 = wm * 64 + m * 16 + (lane & 15);
                af[m] = *(const f16x8*)(&Alds[cur][r2 * BK + ((g ^ (r2 & 7)) << 3)]);
            }
#pragma unroll
            for (int n = 0; n < 4; ++n) {
                const int r2 = wn * 64 + n * 16 + (lane & 15);
                bf[n] = *(const f16x8*)(&Blds[cur][r2 * BK + ((g ^ (r2 & 7)) << 3)]);
            }
#pragma unroll
            for (int m = 0; m < 4; ++m)
#pragma unroll
                for (int n = 0; n < 4; ++n)
                    acc[m][n] = __builtin_amdgcn_mfma_f32_16x16x32_f16(
                        af[m], bf[n], acc[m][n], 0, 0, 0);
        }
        __builtin_amdgcn_s_barrier();   // all ds_reads of cur retired; next
        __builtin_amdgcn_sched_barrier(0);  // iter may overwrite cur buffer
    }
#undef STAGE

    // epilogue: C/D layout col = lane&15, row = (lane>>4)*4 + reg  [m89]
    const int r0 = wm * 64 + (lane >> 4) * 4;
    const int c0 = wn * 64 + (lane & 15);
#pragma unroll
    for (int m = 0; m < 4; ++m)
#pragma unroll
        for (int n = 0; n < 4; ++n)
#pragma unroll
            for (int r = 0; r < 4; ++r)
                unsafeAtomicAdd(&C[(bm + r0 + m * 16 + r) * (size_t)N + bn + c0 + n * 16],
                                acc[m][n][r]);
}

// ---------------------------------------------------------------------------
// launch
// ---------------------------------------------------------------------------
extern "C" void kernel_launch(void* const* d_in, const int* in_sizes, int n_in,
                              void* d_out, int out_size, void* d_ws, size_t ws_size,
                              hipStream_t stream) {
    const float* x     = (const float*)d_in[0];
    const float* coef1 = (const float*)d_in[1];
    const float* sb1   = (const float*)d_in[2];
    const float* sp1   = (const float*)d_in[3];
    const float* coef2 = (const float*)d_in[4];
    const float* sb2   = (const float*)d_in[5];
    const float* sp2   = (const float*)d_in[6];
    float* out = (float*)d_out;

    const int M  = 4096;           // bsz*seq
    const int D1 = 512;            // d_model
    const int D2 = 1024;           // hidden
    const int K1 = 9 * D1;         // 4608
    const int K2 = 9 * D2;         // 9216

    char* ws = (char*)d_ws;
    float*    h    = (float*)ws;                                     // 16.78 MB
    _Float16* Aaug = (_Float16*)(ws + (size_t)M * D2 * 4);           // up to 75.5 MB
    _Float16* WT   = (_Float16*)(ws + (size_t)M * D2 * 4 + (size_t)M * K2 * 2); // 9.44 MB

    hipMemsetAsync(h, 0, (size_t)M * D2 * 4, stream);
    hipMemsetAsync(out, 0, (size_t)M * D1 * 4, stream);

    // ---- layer 1 ----
    prep_w_kernel<<<(D1 * D2) / 256, 256, 0, stream>>>(coef1, sb1, sp1, WT,
                                                       D1 * D2, 9, D2);
    prep_a_kernel<<<(M * D1) / 256, 256, 0, stream>>>(x, Aaug, M * D1, 9);
    {
        dim3 grid(D2 / 128, M / 128, 2);   // split-K x2 -> 512 blocks
        gemm128_f16_bt<<<grid, 256, 0, stream>>>(Aaug, WT, h, K1, D2, K1 / 2, 3);
    }
    // ---- layer 2 ----
    prep_w_kernel<<<(D2 * D1) / 256, 256, 0, stream>>>(coef2, sb2, sp2, WT,
                                                       D1 * D2, 10, D1);
    prep_a_kernel<<<(M * D2) / 256, 256, 0, stream>>>(h, Aaug, M * D2, 10);
    {
        dim3 grid(D1 / 128, M / 128, 4);   // split-K x4 -> 512 blocks
        gemm128_f16_bt<<<grid, 256, 0, stream>>>(Aaug, WT, out, K2, D1, K2 / 4, 2);
    }
}

// Round 6
// 252.630 us; speedup vs baseline: 1.2957x; 1.1046x over previous
//
#include <hip/hip_runtime.h>
#include <hip/hip_bf16.h>
#include <cstdint>
#include <cstddef>

typedef float  f32x4 __attribute__((ext_vector_type(4)));
typedef _Float16 f16x8 __attribute__((ext_vector_type(8)));

#define DEVFN __device__ __forceinline__

// ---------------------------------------------------------------------------
// Cubic B-spline basis on the UNIFORM grid (divisions -> constant multiplies).
// ---------------------------------------------------------------------------
DEVFN void bspline8(float x, float bv[8]) {
    float t[12];
#pragma unroll
    for (int j = 0; j < 12; ++j) t[j] = (float)(j - 3) * 0.4f - 1.0f;
    float B[11];
#pragma unroll
    for (int j = 0; j < 11; ++j) B[j] = (x >= t[j] && x < t[j + 1]) ? 1.0f : 0.0f;
    const float rp[3] = {2.5f, 1.25f, 0.8333333333f};  // 1/(p*0.4)
#pragma unroll
    for (int p = 1; p <= 3; ++p) {
#pragma unroll
        for (int j = 0; j + p < 11; ++j) {
            float left  = (x - t[j]) * rp[p - 1];
            float right = (t[j + p + 1] - x) * rp[p - 1];
            B[j] = left * B[j] + right * B[j + 1];
        }
    }
#pragma unroll
    for (int g = 0; g < 8; ++g) bv[g] = B[g];
}

DEVFN void kan_features(float x, _Float16* dst, int D) {
    float s = x * __builtin_amdgcn_rcpf(1.0f + __expf(-x));   // silu (fast)
    float bv[8];
    bspline8(x, bv);
    dst[0] = (_Float16)s;
#pragma unroll
    for (int g = 0; g < 8; ++g) dst[(size_t)(g + 1) * D] = (_Float16)bv[g];
}

// ---------------------------------------------------------------------------
// prep_a: X (Nrows x D, f32) -> Aaug (Nrows x 9*D, fp16), k = c*D + i
// ---------------------------------------------------------------------------
__global__ void prep_a_kernel(const float* __restrict__ X,
                              _Float16* __restrict__ Aaug,
                              int total, int dshift) {
    int idx = blockIdx.x * 256 + threadIdx.x;
    if (idx >= total) return;
    const int D = 1 << dshift;
    const int K = 9 << dshift;
    const int n = idx >> dshift;
    const int i = idx & (D - 1);
    kan_features(X[idx], Aaug + (size_t)n * K + i, D);
}

// ---------------------------------------------------------------------------
// prep_a_red: like prep_a but input = sum of 4 f32 split-K partials.
// ---------------------------------------------------------------------------
__global__ void prep_a_red_kernel(const float* __restrict__ HP,
                                  _Float16* __restrict__ Aaug,
                                  int total, int dshift, size_t pstride) {
    int idx = blockIdx.x * 256 + threadIdx.x;
    if (idx >= total) return;
    const int D = 1 << dshift;
    const int K = 9 << dshift;
    const int n = idx >> dshift;
    const int i = idx & (D - 1);
    float x = (HP[idx] + HP[idx + pstride]) +
              (HP[idx + 2 * pstride] + HP[idx + 3 * pstride]);
    kan_features(x, Aaug + (size_t)n * K + i, D);
}

// ---------------------------------------------------------------------------
// reduce_out: out = sum of 8 f32 partials (float4-vectorized).
// ---------------------------------------------------------------------------
__global__ void reduce_out_kernel(const float* __restrict__ OP,
                                  float* __restrict__ out,
                                  int total4, size_t pstride4) {
    int i = blockIdx.x * 256 + threadIdx.x;
    if (i >= total4) return;
    const f32x4* p = (const f32x4*)OP;
    f32x4 s = p[i];
#pragma unroll
    for (int k = 1; k < 8; ++k) s += p[i + k * pstride4];
    ((f32x4*)out)[i] = s;
}

// ---------------------------------------------------------------------------
// prep_w: coef (Din x Dout x 8), scale_base/scale_sp (Din x Dout)
//   -> WT (Dout x 9*Din, fp16)
// ---------------------------------------------------------------------------
__global__ void prep_w_kernel(const float* __restrict__ coef,
                              const float* __restrict__ sb,
                              const float* __restrict__ sp,
                              _Float16* __restrict__ WT,
                              int total, int din_shift, int dout) {
    int idx = blockIdx.x * 256 + threadIdx.x;
    if (idx >= total) return;
    const int Din = 1 << din_shift;
    const int i = idx & (Din - 1);
    const int o = idx >> din_shift;
    const size_t K = (size_t)9 << din_shift;
    const size_t cidx = (size_t)i * dout + o;
    float base  = sb[cidx];
    float scale = sp[cidx];
    const float* cp = coef + cidx * 8;
    _Float16* dst = WT + (size_t)o * K + i;
    dst[0] = (_Float16)base;
#pragma unroll
    for (int g = 0; g < 8; ++g) dst[(size_t)(g + 1) * Din] = (_Float16)(cp[g] * scale);
}

// ---------------------------------------------------------------------------
// GEMM 256x256 tile, BK=64, 8 waves (2M x 4N), per-wave 128x64 output
// (8x4 frags of 16x16x32 f16 MFMA). Same proven 2-phase pipeline as R5:
// double-buffered LDS (128 KB), STAGE(next) before compute, raw s_barrier +
// counted s_waitcnt vmcnt(8). T2 XOR swizzle (linear LDS dest + pre-swizzled
// global source + swizzled ds_read). Split-K writes PLAIN f32 partials
// (no atomics); reduction fused into prep_a_red / reduce_out.
// T1 XCD-aware block swizzle (bijective, nwg % 8 == 0, gridDim.y == 16).
// ---------------------------------------------------------------------------
DEVFN void gload16(const void* g, void* l) {
    __builtin_amdgcn_global_load_lds(
        (const __attribute__((address_space(1))) void*)g,
        (__attribute__((address_space(3))) void*)l, 16, 0, 0);
}

__global__ __launch_bounds__(512, 2) void gemm256_f16_bt(
    const _Float16* __restrict__ A,
    const _Float16* __restrict__ WT,
    float* __restrict__ P,
    int K, int N, int klen, int gxshift) {
    constexpr int BK = 64;
    __shared__ _Float16 Alds[2][256 * BK];   // 64 KB
    __shared__ _Float16 Blds[2][256 * BK];   // 64 KB

    const int tid  = threadIdx.x;
    const int lane = tid & 63;
    const int w    = tid >> 6;          // 0..7
    const int wm   = w >> 2;            // 0..1
    const int wn   = w & 3;             // 0..3

    // ---- T1 XCD swizzle (nwg = gx*16*gz, multiple of 8) ----
    const int gx   = 1 << gxshift;
    const int nwg  = gx * 16 * gridDim.z;
    const int orig = blockIdx.x + (blockIdx.y << gxshift) + blockIdx.z * (gx * 16);
    const int tile = (orig & 7) * (nwg >> 3) + (orig >> 3);
    const int col  = tile & (gx - 1);
    const int rs   = tile >> gxshift;
    const int row  = rs & 15;           // gridDim.y == 16
    const int spl  = rs >> 4;

    const size_t bm = (size_t)row * 256;
    const size_t bn = (size_t)col * 256;
    const int kbase = spl * klen;
    const int nt    = klen / BK;
    float* Cp = P + (size_t)spl * 4096 * N;   // M = 4096

    const f32x4 vzero = {0.0f, 0.0f, 0.0f, 0.0f};
    f32x4 acc[8][4];
#pragma unroll
    for (int m = 0; m < 8; ++m)
#pragma unroll
        for (int n = 0; n < 4; ++n) acc[m][n] = vzero;

    const int srow = tid >> 3;          // 0..63
    const int c8   = tid & 7;
    const int ldst = w * 512;           // wave-uniform LDS base (halfs)

    // 8 async loads (4 A + 4 B) of K-tile kk into buffer b
#define STAGE(b, kk)                                                         \
    {                                                                        \
        _Pragma("unroll")                                                    \
        for (int is = 0; is < 4; ++is) {                                     \
            const int r  = is * 64 + srow;                                   \
            const int sg = (c8 ^ (r & 7)) << 3;                              \
            gload16(A + (bm + r) * (size_t)K + (kk) + sg,                    \
                    &Alds[b][is * 4096 + ldst]);                             \
            gload16(WT + (bn + r) * (size_t)K + (kk) + sg,                   \
                    &Blds[b][is * 4096 + ldst]);                             \
        }                                                                    \
    }

    STAGE(0, kbase);                     // prologue: buf0 in flight (8)

    for (int t = 0; t < nt; ++t) {
        const int cur = t & 1;
        if (t + 1 < nt) {
            STAGE(cur ^ 1, kbase + (t + 1) * BK);            // 16 in flight
            asm volatile("s_waitcnt vmcnt(8)" ::: "memory"); // cur's 8 done
        } else {
            asm volatile("s_waitcnt vmcnt(0)" ::: "memory");
        }
        __builtin_amdgcn_s_barrier();          // all waves: cur buffer ready
        __builtin_amdgcn_sched_barrier(0);

#pragma unroll
        for (int ks = 0; ks < BK; ks += 32) {
            f16x8 af[8], bf[4];
            const int g = (ks >> 3) + (lane >> 4);      // k col-group 0..7
#pragma unroll
            for (int m = 0; m < 8; ++m) {
                const int r2 = wm * 128 + m * 16 + (lane & 15);
                af[m] = *(const f16x8*)(&Alds[cur][r2 * BK + ((g ^ (r2 & 7)) << 3)]);
            }
#pragma unroll
            for (int n = 0; n < 4; ++n) {
                const int r2 = wn * 64 + n * 16 + (lane & 15);
                bf[n] = *(const f16x8*)(&Blds[cur][r2 * BK + ((g ^ (r2 & 7)) << 3)]);
            }
#pragma unroll
            for (int m = 0; m < 8; ++m)
#pragma unroll
                for (int n = 0; n < 4; ++n)
                    acc[m][n] = __builtin_amdgcn_mfma_f32_16x16x32_f16(
                        af[m], bf[n], acc[m][n], 0, 0, 0);
        }
        __builtin_amdgcn_s_barrier();   // all ds_reads of cur retired; next
        __builtin_amdgcn_sched_barrier(0);  // iter may overwrite cur buffer
    }
#undef STAGE

    // epilogue: C/D layout col = lane&15, row = (lane>>4)*4 + reg  [m89]
    const int r0 = wm * 128 + (lane >> 4) * 4;
    const int c0 = wn * 64 + (lane & 15);
#pragma unroll
    for (int m = 0; m < 8; ++m)
#pragma unroll
        for (int n = 0; n < 4; ++n)
#pragma unroll
            for (int r = 0; r < 4; ++r)
                Cp[(bm + r0 + m * 16 + r) * (size_t)N + bn + c0 + n * 16] =
                    acc[m][n][r];
}

// ---------------------------------------------------------------------------
// launch
// ---------------------------------------------------------------------------
extern "C" void kernel_launch(void* const* d_in, const int* in_sizes, int n_in,
                              void* d_out, int out_size, void* d_ws, size_t ws_size,
                              hipStream_t stream) {
    const float* x     = (const float*)d_in[0];
    const float* coef1 = (const float*)d_in[1];
    const float* sb1   = (const float*)d_in[2];
    const float* sp1   = (const float*)d_in[3];
    const float* coef2 = (const float*)d_in[4];
    const float* sb2   = (const float*)d_in[5];
    const float* sp2   = (const float*)d_in[6];
    float* out = (float*)d_out;

    const int M  = 4096;           // bsz*seq
    const int D1 = 512;            // d_model
    const int D2 = 1024;           // hidden
    const int K1 = 9 * D1;         // 4608
    const int K2 = 9 * D2;         // 9216

    char* ws = (char*)d_ws;
    _Float16* Aaug = (_Float16*)ws;                         // 75.5 MB (max)
    _Float16* WT   = (_Float16*)(ws + (size_t)M * K2 * 2);  // 9.44 MB
    float*    P    = (float*)(ws + (size_t)M * K2 * 2 +
                              (size_t)D1 * K2 * 2);         // 67.1 MB shared partials

    // ---- layer 1 ----
    prep_w_kernel<<<(D1 * D2) / 256, 256, 0, stream>>>(coef1, sb1, sp1, WT,
                                                       D1 * D2, 9, D2);
    prep_a_kernel<<<(M * D1) / 256, 256, 0, stream>>>(x, Aaug, M * D1, 9);
    {
        dim3 grid(D2 / 256, M / 256, 4);   // 4x16x4 = 256 blocks (1/CU)
        gemm256_f16_bt<<<grid, 512, 0, stream>>>(Aaug, WT, P, K1, D2, K1 / 4, 2);
    }
    // ---- layer 2 (prep_a fuses the 4-way split-K reduction of h) ----
    prep_w_kernel<<<(D2 * D1) / 256, 256, 0, stream>>>(coef2, sb2, sp2, WT,
                                                       D1 * D2, 10, D1);
    prep_a_red_kernel<<<(M * D2) / 256, 256, 0, stream>>>(P, Aaug, M * D2, 10,
                                                          (size_t)M * D2);
    {
        dim3 grid(D1 / 256, M / 256, 8);   // 2x16x8 = 256 blocks (1/CU)
        gemm256_f16_bt<<<grid, 512, 0, stream>>>(Aaug, WT, P, K2, D1, K2 / 8, 1);
    }
    reduce_out_kernel<<<(M * D1 / 4) / 256, 256, 0, stream>>>(
        P, out, M * D1 / 4, (size_t)M * D1 / 4);
}